// Round 11
// baseline (5971.398 us; speedup 1.0000x reference)
//
#include <hip/hip_runtime.h>
#include <hip/hip_cooperative_groups.h>

namespace cg = cooperative_groups;

typedef unsigned short u16;
typedef __bf16 bf16x8 __attribute__((ext_vector_type(8)));
typedef float f32x4 __attribute__((ext_vector_type(4)));
typedef unsigned short u16x4 __attribute__((ext_vector_type(4)));

__device__ __forceinline__ u16 f2bf(float f) {
  union { float f; unsigned int u; } v; v.f = f;
  return (u16)((v.u + 0x7FFFu + ((v.u >> 16) & 1u)) >> 16);
}

__device__ __forceinline__ void gload16(const void* g, void* l) {
  __builtin_amdgcn_global_load_lds(
      (const __attribute__((address_space(1))) unsigned int*)g,
      (__attribute__((address_space(3))) unsigned int*)l, 16, 0, 0);
}

// ---------------------------------------------------------------------------
// prep_weights: ALL weight transposes in ONE dispatch (validated r9/r10).
// ---------------------------------------------------------------------------
__global__ void prep_weights(const float* __restrict__ Win,
                             const float* __restrict__ Wout,
                             const float* __restrict__ ffw1,
                             const float* __restrict__ ffw2,
                             u16* __restrict__ WinT, u16* __restrict__ WoutT,
                             u16* __restrict__ f1T, u16* __restrict__ f2T) {
  __shared__ float tile[32][33];
  const int tk = blockIdx.x;
  const float* src; u16* dst;
  int R, C, tr, tc;
  if (tk < 8192) {
    const int l = tk >> 10, rem = tk & 1023;
    R = 1024; C = 1024; tr = rem >> 5; tc = rem & 31;
    src = Win + (size_t)l * 1048576; dst = WinT + (size_t)l * 1048576;
  } else if (tk < 16384) {
    const int q = tk - 8192, l = q >> 10, rem = q & 1023;
    R = 1024; C = 1024; tr = rem >> 5; tc = rem & 31;
    src = Wout + (size_t)l * 1048576; dst = WoutT + (size_t)l * 1048576;
  } else if (tk < 32768) {
    const int q = tk - 16384, l = q >> 11, rem = q & 2047;
    R = 1024; C = 2048; tr = rem >> 6; tc = rem & 63;
    src = ffw1 + (size_t)l * 2097152; dst = f1T + (size_t)l * 2097152;
  } else {
    const int q = tk - 32768, l = q >> 11, rem = q & 2047;
    R = 2048; C = 1024; tr = rem >> 5; tc = rem & 31;
    src = ffw2 + (size_t)l * 2097152; dst = f2T + (size_t)l * 2097152;
  }
  const int tx = threadIdx.x, ty = threadIdx.y;
  const int c0 = tc * 32, r0 = tr * 32;
#pragma unroll
  for (int k = 0; k < 32; k += 8)
    tile[ty + k][tx] = src[(size_t)(r0 + ty + k) * C + (c0 + tx)];
  __syncthreads();
#pragma unroll
  for (int k = 0; k < 32; k += 8)
    dst[(size_t)(c0 + ty + k) * R + (r0 + tx)] = f2bf(tile[tx][ty + k]);
}

// ---------------------------------------------------------------------------
// Fallback-path kernels (validated round 8/10)
// ---------------------------------------------------------------------------
__global__ void lm_cast_kernel(const float* __restrict__ lm, u16* __restrict__ out) {
  const int row = blockIdx.x;
  const int t = threadIdx.x;
  u16x4 o = {0, 0, 0, 0};
  if (row < 50257) {
    float4 v = *(const float4*)(lm + (size_t)row * 1024 + t * 4);
    o.x = f2bf(v.x); o.y = f2bf(v.y); o.z = f2bf(v.z); o.w = f2bf(v.w);
  }
  *(u16x4*)(out + (size_t)row * 1024 + t * 4) = o;
}

__global__ void embed_kernel(const int* __restrict__ ids, const float* __restrict__ embed,
                             float* __restrict__ x) {
  const int row = blockIdx.x;
  const int id = ids[row];
  const int t = threadIdx.x;
  *(float4*)(x + (size_t)row * 1024 + t * 4) =
      *(const float4*)(embed + (size_t)id * 1024 + t * 4);
}

__global__ void rmsnorm_kernel(const float* __restrict__ x, const float* __restrict__ w,
                               u16* __restrict__ out) {
  const int row = blockIdx.x, tid = threadIdx.x;
  const float* xr = x + (size_t)row * 1024;
  float4 v = *(const float4*)(xr + tid * 4);
  float ss = v.x * v.x + v.y * v.y + v.z * v.z + v.w * v.w;
#pragma unroll
  for (int off = 32; off; off >>= 1) ss += __shfl_xor(ss, off);
  __shared__ float red[4];
  if ((tid & 63) == 0) red[tid >> 6] = ss;
  __syncthreads();
  const float tot = red[0] + red[1] + red[2] + red[3];
  const float r = rsqrtf(tot * (1.0f / 1024.0f) + 1e-6f);
  float4 wv = *(const float4*)(w + tid * 4);
  u16x4 o;
  o.x = f2bf(v.x * r * wv.x); o.y = f2bf(v.y * r * wv.y);
  o.z = f2bf(v.z * r * wv.z); o.w = f2bf(v.w * r * wv.w);
  *(u16x4*)(out + (size_t)row * 1024 + tid * 4) = o;
}

// scan helpers (shared by fallback kernel and mega phase)
__device__ __forceinline__ void sload(const float* __restrict__ p, int tb,
                                      float A2b, float (&buf)[8]) {
#pragma unroll
  for (int j = 0; j < 8; j++)
    buf[j] = fmaf(p[(size_t)(tb + j) * 1024], 2.8853900817779268f, A2b);
}

__device__ __forceinline__ void scomp(float (&buf)[8], float m2A2, float& r,
                                      u16* __restrict__ o, int tb) {
#pragma unroll
  for (int j = 0; j < 8; j++) {
    float z = fmaf(m2A2, r, buf[j]);
    float e = __builtin_amdgcn_exp2f(z);
    r = __builtin_amdgcn_rcpf(1.0f + e);
    o[(size_t)(tb + j) * 1024] = f2bf(fmaf(-2.0f, r, 1.0f));
  }
}

__device__ __forceinline__ void scan_chain(const float* __restrict__ p,
                                           u16* __restrict__ o, float A2,
                                           float A2b) {
  const float m2A2 = -2.0f * A2;
  float r = 0.5f;
  float b0[8], b1[8], b2[8], b3[8];
  sload(p, 0, A2b, b0); sload(p, 8, A2b, b1);
  sload(p, 16, A2b, b2); sload(p, 24, A2b, b3);
  for (int t0 = 0; t0 < 2048; t0 += 32) {
    scomp(b0, m2A2, r, o, t0);
    if (t0 + 32 < 2048) sload(p, t0 + 32, A2b, b0);
    scomp(b1, m2A2, r, o, t0 + 8);
    if (t0 + 32 < 2048) sload(p, t0 + 40, A2b, b1);
    scomp(b2, m2A2, r, o, t0 + 16);
    if (t0 + 32 < 2048) sload(p, t0 + 48, A2b, b2);
    scomp(b3, m2A2, r, o, t0 + 24);
    if (t0 + 32 < 2048) sload(p, t0 + 56, A2b, b3);
  }
}

__global__ __launch_bounds__(256) void scan_kernel(const float* __restrict__ pre,
                                                   const float* __restrict__ a_diag,
                                                   const float* __restrict__ b_in,
                                                   u16* __restrict__ hs) {
  const int idx = blockIdx.x * 256 + threadIdx.x;  // 0..2047
  const int b = idx >> 10, d = idx & 1023;
  const float A2 = a_diag[d] * 2.8853900817779268f;
  const float A2b = fmaf(2.8853900817779268f, b_in[d], A2);
  scan_chain(pre + (size_t)b * 2097152 + d, hs + (size_t)b * 2097152 + d, A2, A2b);
}

// gemmL: round-8 validated double-buffer 64x128 layer GEMM (fallback path).
template <int EPI>
__global__ __launch_bounds__(256) void gemmL(
    const u16* __restrict__ A, int lda, const u16* __restrict__ Bw, int ldb,
    const float* __restrict__ bias, float* Cf, u16* __restrict__ Cb,
    int ldc, int K) {
  __shared__ char lds[49152];
  const int tid = threadIdx.x;
  const int lane = tid & 63;
  const int wc = tid >> 6;
  const int tm = blockIdx.y * 64, tn = blockIdx.x * 128;
  const int lr = lane & 15;
  const int sb0 = ((lane >> 4) ^ (lane & 7)) << 4;

  const int srow = tid >> 3;
  const int sxs = ((tid & 7) ^ (srow & 7)) << 4;
  const char* pA = (const char*)A + (size_t)(tm + srow) * lda * 2 + sxs;
  const char* pB = (const char*)Bw + (size_t)(tn + srow) * ldb * 2 + sxs;
  const size_t a32 = (size_t)lda * 64;
  const size_t b32 = (size_t)ldb * 64;

#define STGL(kt, bufo)                                \
  {                                                   \
    char* d = lds + (bufo) + tid * 16;                \
    const size_t kb = (size_t)(kt) << 7;              \
    gload16(pA + kb, d);                              \
    gload16(pA + a32 + kb, d + 4096);                 \
    gload16(pB + kb, d + 8192);                       \
    gload16(pB + b32 + kb, d + 12288);                \
    gload16(pB + 2 * b32 + kb, d + 16384);            \
    gload16(pB + 3 * b32 + kb, d + 20480);            \
  }

  f32x4 acc[4][2] = {};
  const int nkt = K >> 6;

  STGL(0, 0);
  int cur = 0;
  for (int kt = 0; kt < nkt; ++kt) {
    if (kt + 1 < nkt) {
      STGL(kt + 1, (cur ^ 1) * 24576);
      asm volatile("s_waitcnt vmcnt(6)" ::: "memory");
    } else {
      asm volatile("s_waitcnt vmcnt(0)" ::: "memory");
    }
    __builtin_amdgcn_s_barrier();
    const char* base = lds + cur * 24576;
    bf16x8 aF[4][2], bF[2][2];
#pragma unroll
    for (int m = 0; m < 4; m++)
#pragma unroll
      for (int ks = 0; ks < 2; ks++)
        aF[m][ks] =
            *(const bf16x8*)(base + (m * 16 + lr) * 128 + (sb0 ^ (ks << 6)));
#pragma unroll
    for (int n = 0; n < 2; n++)
#pragma unroll
      for (int ks = 0; ks < 2; ks++)
        bF[n][ks] = *(const bf16x8*)(base + 8192 +
                                     (wc * 32 + n * 16 + lr) * 128 +
                                     (sb0 ^ (ks << 6)));
#pragma unroll
    for (int ks = 0; ks < 2; ks++)
#pragma unroll
      for (int m = 0; m < 4; m++)
#pragma unroll
        for (int n = 0; n < 2; n++)
          acc[m][n] = __builtin_amdgcn_mfma_f32_16x16x32_bf16(
              aF[m][ks], bF[n][ks], acc[m][n], 0, 0, 0);
    __builtin_amdgcn_s_barrier();
    cur ^= 1;
  }
#undef STGL

  const int crow = tm + ((lane >> 4) << 2);
  const int ccol = tn + wc * 32 + lr;
#pragma unroll
  for (int m = 0; m < 4; m++) {
#pragma unroll
    for (int n = 0; n < 2; n++) {
      const int cg = ccol + n * 16;
      float bb = 0.0f;
      if (EPI == 2 || EPI == 3) bb = bias[cg];
#pragma unroll
      for (int j = 0; j < 4; j++) {
        const size_t off = (size_t)(crow + m * 16 + j) * ldc + cg;
        const float v = acc[m][n][j] + bb;
        if (EPI == 0) {
          Cf[off] = v;
        } else if (EPI == 1) {
          Cf[off] += v;
        } else if (EPI == 2) {
          const float sg = __builtin_amdgcn_rcpf(
              1.0f + __builtin_amdgcn_exp2f(-1.4426950408889634f * v));
          Cb[off] = f2bf(v * sg);
        } else {
          Cf[off] += v;
        }
      }
    }
  }
}

// ---------------------------------------------------------------------------
// MEGA cooperative kernel: lm_cast + embed + 8 layers + final norm.
// 256 blocks x 512 threads (1 block/CU, co-resident), grid.sync() between
// phases. Removes ~59 dependent-dispatch boundaries (~30us each measured
// structure-invariant across r3-r10).
// ---------------------------------------------------------------------------

// GEMM phase: 128x128 tile, BK=64, 8 waves (2x4), dbuf vmcnt(4).
// EPI: 0 Cf=v; 1 Cf+=v; 2 Cb=silu(v+bias); 3 Cf+=v+bias
template <int EPI>
__device__ __forceinline__ void gemm_phase(
    char* lds, const u16* __restrict__ A, int lda,
    const u16* __restrict__ B, int ldb, const float* __restrict__ bias,
    float* __restrict__ Cf, u16* __restrict__ Cb, int ldc,
    int ntm, int ntn, int K) {
  const int tid = threadIdx.x;
  const int lane = tid & 63;
  const int wid = tid >> 6;
  const int wr = wid >> 2, wc = wid & 3;
  const int lr = lane & 15;
  const int sb0 = ((lane >> 4) ^ (lane & 7)) << 4;
  const int srow = tid >> 3;  // 0..63
  const int sxs = ((tid & 7) ^ (srow & 7)) << 4;
  const int nkt = K >> 6;
  const int ntiles = ntm * ntn;

  for (int t = blockIdx.x; t < ntiles; t += gridDim.x) {
    const int tm = (t / ntn) << 7, tn = (t % ntn) << 7;
    const char* pA = (const char*)A + (size_t)(tm + srow) * lda * 2 + sxs;
    const char* pB = (const char*)B + (size_t)(tn + srow) * ldb * 2 + sxs;
    const size_t pA2 = (size_t)lda << 7;  // +64 rows
    const size_t pB2 = (size_t)ldb << 7;
    f32x4 acc[4][2] = {};
    __syncthreads();  // previous tile fully read before restaging buf0
    {
      char* d = lds + tid * 16;
      gload16(pA, d); gload16(pA + pA2, d + 8192);
      gload16(pB, d + 16384); gload16(pB + pB2, d + 24576);
    }
    int cur = 0;
    for (int kt = 0; kt < nkt; ++kt) {
      if (kt + 1 < nkt) {
        const size_t kb = (size_t)(kt + 1) << 7;
        char* d = lds + (cur ^ 1) * 32768 + tid * 16;
        gload16(pA + kb, d); gload16(pA + pA2 + kb, d + 8192);
        gload16(pB + kb, d + 16384); gload16(pB + pB2 + kb, d + 24576);
        asm volatile("s_waitcnt vmcnt(4)" ::: "memory");
      } else {
        asm volatile("s_waitcnt vmcnt(0)" ::: "memory");
      }
      __builtin_amdgcn_s_barrier();
      const char* base = lds + cur * 32768;
      bf16x8 aF[4][2], bF[2][2];
#pragma unroll
      for (int m = 0; m < 4; m++)
#pragma unroll
        for (int ks = 0; ks < 2; ks++)
          aF[m][ks] = *(const bf16x8*)(base + (wr * 64 + m * 16 + lr) * 128 +
                                       (sb0 ^ (ks << 6)));
#pragma unroll
      for (int n = 0; n < 2; n++)
#pragma unroll
        for (int ks = 0; ks < 2; ks++)
          bF[n][ks] = *(const bf16x8*)(base + 16384 +
                                       (wc * 32 + n * 16 + lr) * 128 +
                                       (sb0 ^ (ks << 6)));
#pragma unroll
      for (int ks = 0; ks < 2; ks++)
#pragma unroll
        for (int m = 0; m < 4; m++)
#pragma unroll
          for (int n = 0; n < 2; n++)
            acc[m][n] = __builtin_amdgcn_mfma_f32_16x16x32_bf16(
                aF[m][ks], bF[n][ks], acc[m][n], 0, 0, 0);
      __builtin_amdgcn_s_barrier();
      cur ^= 1;
    }
    const int crow = tm + wr * 64 + ((lane >> 4) << 2);
    const int ccol = tn + wc * 32 + lr;
#pragma unroll
    for (int m = 0; m < 4; m++) {
#pragma unroll
      for (int n = 0; n < 2; n++) {
        const int cg = ccol + n * 16;
#pragma unroll
        for (int j = 0; j < 4; j++) {
          const size_t off = (size_t)(crow + m * 16 + j) * ldc + cg;
          const float v = acc[m][n][j];
          if (EPI == 0) {
            Cf[off] = v;
          } else if (EPI == 1) {
            Cf[off] += v;
          } else if (EPI == 2) {
            const float vb = v + bias[cg];
            const float sg = __builtin_amdgcn_rcpf(
                1.0f + __builtin_amdgcn_exp2f(-1.4426950408889634f * vb));
            Cb[off] = f2bf(vb * sg);
          } else {
            Cf[off] += v + bias[cg];
          }
        }
      }
    }
  }
}

// RMSNorm phase: 16 rows/block, 2 rows at a time (256 threads each).
__device__ __forceinline__ void norm_phase(const float* __restrict__ xg,
                                           const float* __restrict__ w,
                                           u16* __restrict__ hg,
                                           volatile float* red) {
  const int tid = threadIdx.x;
  const int sub = tid >> 8, t = tid & 255;
#pragma unroll 1
  for (int i = 0; i < 8; i++) {
    const int row = blockIdx.x * 16 + i * 2 + sub;
    const size_t ro = (size_t)row * 1024 + t * 4;
    float4 v = *(const float4*)(xg + ro);
    float ss = v.x * v.x + v.y * v.y + v.z * v.z + v.w * v.w;
#pragma unroll
    for (int off = 32; off; off >>= 1) ss += __shfl_xor(ss, off);
    __syncthreads();
    if ((tid & 63) == 0) red[tid >> 6] = ss;
    __syncthreads();
    const float tot =
        red[sub * 4] + red[sub * 4 + 1] + red[sub * 4 + 2] + red[sub * 4 + 3];
    const float rr = rsqrtf(tot * (1.0f / 1024.0f) + 1e-6f);
    float4 wv = *(const float4*)(w + t * 4);
    u16x4 o;
    o.x = f2bf(v.x * rr * wv.x); o.y = f2bf(v.y * rr * wv.y);
    o.z = f2bf(v.z * rr * wv.z); o.w = f2bf(v.w * rr * wv.w);
    *(u16x4*)(hg + ro) = o;
  }
}

__global__ __launch_bounds__(512, 1) void mega(
    const int* __restrict__ ids, const float* __restrict__ embedw,
    const float* __restrict__ n1w, const float* __restrict__ n2w,
    const float* __restrict__ adiag, const float* __restrict__ bin,
    const float* __restrict__ fb1, const float* __restrict__ fb2,
    const float* __restrict__ finw, const float* __restrict__ lmw,
    float* __restrict__ x, u16* __restrict__ h, float* __restrict__ pre,
    u16* __restrict__ hs, u16* __restrict__ hff,
    const u16* __restrict__ WinT, const u16* __restrict__ WoutT,
    const u16* __restrict__ f1T, const u16* __restrict__ f2T,
    u16* __restrict__ lmpad) {
  __shared__ char smem[65536];
  __shared__ float red[16];
  cg::grid_group grid = cg::this_grid();
  const int bid = blockIdx.x;
  const int tid = threadIdx.x;

  // ---- phase 0: lm cast + embed ----
  for (int row = bid; row < 50432; row += 256) {
    unsigned int o = 0;
    if (row < 50257) {
      float2 v = *(const float2*)(lmw + (size_t)row * 1024 + tid * 2);
      o = (unsigned int)f2bf(v.x) | ((unsigned int)f2bf(v.y) << 16);
    }
    *(unsigned int*)(lmpad + (size_t)row * 1024 + tid * 2) = o;
  }
  for (int row = bid; row < 4096; row += 256) {
    const float2 v =
        *(const float2*)(embedw + (size_t)ids[row] * 1024 + tid * 2);
    *(float2*)(x + (size_t)row * 1024 + tid * 2) = v;
  }
  grid.sync();

  // ---- layers ----
  for (int l = 0; l < 8; ++l) {
    norm_phase(x, n1w + l * 1024, h, red);
    grid.sync();
    gemm_phase<0>(smem, h, 1024, WinT + (size_t)l * 1048576, 1024, nullptr,
                  pre, nullptr, 1024, 32, 8, 1024);
    grid.sync();
    if (bid < 4) {
      const int idx = bid * 512 + tid;  // 0..2047
      const int b = idx >> 10, d = idx & 1023;
      const float A2 = adiag[l * 1024 + d] * 2.8853900817779268f;
      const float A2b = fmaf(2.8853900817779268f, bin[l * 1024 + d], A2);
      scan_chain(pre + (size_t)b * 2097152 + d, hs + (size_t)b * 2097152 + d,
                 A2, A2b);
    }
    grid.sync();
    gemm_phase<1>(smem, hs, 1024, WoutT + (size_t)l * 1048576, 1024, nullptr,
                  x, nullptr, 1024, 32, 8, 1024);
    grid.sync();
    norm_phase(x, n2w + l * 1024, h, red);
    grid.sync();
    gemm_phase<2>(smem, h, 1024, f1T + (size_t)l * 2097152, 1024,
                  fb1 + l * 2048, nullptr, hff, 2048, 32, 16, 1024);
    grid.sync();
    gemm_phase<3>(smem, hff, 2048, f2T + (size_t)l * 2097152, 2048,
                  fb2 + l * 1024, x, nullptr, 1024, 32, 8, 2048);
    grid.sync();
  }

  // ---- final norm ----
  norm_phase(x, finw, h, red);
}

// ---------------------------------------------------------------------------
// gemm_lm8: 256x256 / BK=64 / 8 waves / 8-phase counted-vmcnt, plain stores
// (round-9/10 validated: ~520us).
// ---------------------------------------------------------------------------
__global__ __launch_bounds__(512, 2) void gemm_lm8(
    const u16* __restrict__ A, const u16* __restrict__ Bw,
    float* __restrict__ C, int Nreal) {
  __shared__ char lds[131072];
  const int tid = threadIdx.x;
  const int lane = tid & 63;
  const int wid = tid >> 6;
  const int wr = wid >> 2;
  const int wc = wid & 3;
  const int bid = blockIdx.x;
  const int tm = (((bid & 7) << 1) + ((bid >> 3) & 1)) << 8;
  const int tn = (bid >> 4) << 8;

  const int srow = tid >> 3;
  const int sxor = ((tid & 7) ^ (srow & 7)) << 4;
  const char* pAs = (const char*)A + ((size_t)(tm + srow) << 11) + sxor;
  const char* pBs = (const char*)Bw + ((size_t)(tn + srow) << 11) + sxor;

#define STG(p, h, kt, ro)                                      \
  {                                                            \
    char* d = lds + (ro) + tid * 16;                           \
    const char* s = (p) + ((size_t)(h) << 18) + ((kt) << 7);   \
    gload16(s, d);                                             \
    gload16(s + (64ull << 11), d + 8192);                      \
  }

  const int lr = lane & 15;
  const int sb0 = (((lane >> 4) ^ (lane & 7)) << 4);
  const int sb[2] = {sb0, sb0 ^ 64};
  const int aB = wr * 16384 + lr * 128;
  const int bB = 32768 + (wc >> 1) * 16384 + ((wc & 1) * 64 + lr) * 128;

  bf16x8 aR[4][2], bR[2][2][2];
  f32x4 acc[8][4] = {};

#define LDA_Q(bufo, mq)                                                         \
  _Pragma("unroll") for (int m_ = 0; m_ < 4; m_++)                              \
  _Pragma("unroll") for (int k_ = 0; k_ < 2; k_++)                              \
      aR[m_][k_] = *(const bf16x8*)(lds + (bufo) + aB + (mq)*8192 + m_*2048 + sb[k_]);

#define LDB_Q(bufo, nq)                                                         \
  _Pragma("unroll") for (int n_ = 0; n_ < 2; n_++)                              \
  _Pragma("unroll") for (int k_ = 0; k_ < 2; k_++)                              \
      bR[nq][n_][k_] = *(const bf16x8*)(lds + (bufo) + bB + (nq)*4096 + n_*2048 + sb[k_]);

#define MFMA_Q(mq, nq)                                                          \
  __builtin_amdgcn_s_setprio(1);                                                \
  _Pragma("unroll") for (int m_ = 0; m_ < 4; m_++)                              \
  _Pragma("unroll") for (int n_ = 0; n_ < 2; n_++)                              \
  _Pragma("unroll") for (int k_ = 0; k_ < 2; k_++)                              \
      acc[(mq)*4 + m_][(nq)*2 + n_] = __builtin_amdgcn_mfma_f32_16x16x32_bf16(  \
          aR[m_][k_], bR[nq][n_][k_], acc[(mq)*4 + m_][(nq)*2 + n_], 0, 0, 0);  \
  __builtin_amdgcn_s_setprio(0);

#define BAR() __builtin_amdgcn_s_barrier()
#define LGKM0() asm volatile("s_waitcnt lgkmcnt(0)" ::: "memory")

  STG(pAs, 0, 0, 0);
  STG(pAs, 1, 0, 16384);
  STG(pBs, 0, 0, 32768);
  STG(pBs, 1, 0, 49152);
  STG(pBs, 0, 1, 65536 + 32768);
  STG(pBs, 1, 1, 65536 + 49152);
  asm volatile("s_waitcnt vmcnt(4)" ::: "memory");
  BAR();

  for (int it = 0; it < 8; ++it) {
    const int t1 = 2 * it + 1, t2 = 2 * it + 2, t3 = 2 * it + 3;
    const bool st = (it < 7);
    LDA_Q(0, 0); LDB_Q(0, 0);
    STG(pAs, 0, t1, 65536);
    BAR(); LGKM0(); MFMA_Q(0, 0); BAR();
    LDB_Q(0, 1);
    STG(pAs, 1, t1, 65536 + 16384);
    BAR(); LGKM0(); MFMA_Q(0, 1); BAR();
    LDA_Q(0, 1);
    if (st) STG(pBs, 0, t2, 32768);
    BAR(); LGKM0(); MFMA_Q(1, 0); BAR();
    if (st) STG(pBs, 1, t2, 49152);
    BAR(); LGKM0(); MFMA_Q(1, 1);
    if (st) { asm volatile("s_waitcnt vmcnt(4)" ::: "memory"); }
    else    { asm volatile("s_waitcnt vmcnt(0)" ::: "memory"); }
    BAR();
    LDA_Q(65536, 0); LDB_Q(65536, 0);
    if (st) STG(pAs, 0, t2, 0);
    BAR(); LGKM0(); MFMA_Q(0, 0); BAR();
    LDB_Q(65536, 1);
    if (st) STG(pAs, 1, t2, 16384);
    BAR(); LGKM0(); MFMA_Q(0, 1); BAR();
    LDA_Q(65536, 1);
    if (st) STG(pBs, 0, t3, 65536 + 32768);
    BAR(); LGKM0(); MFMA_Q(1, 0); BAR();
    if (st) STG(pBs, 1, t3, 65536 + 49152);
    BAR(); LGKM0(); MFMA_Q(1, 1);
    if (st) { asm volatile("s_waitcnt vmcnt(4)" ::: "memory"); }
    else    { asm volatile("s_waitcnt vmcnt(0)" ::: "memory"); }
    BAR();
  }
#undef STG
#undef LDA_Q
#undef LDB_Q
#undef MFMA_Q
#undef BAR
#undef LGKM0

  const int crow = tm + wr * 128 + ((lane >> 4) << 2);
  const int ccol = tn + wc * 64 + lr;
#pragma unroll
  for (int M_ = 0; M_ < 8; M_++) {
    const int r = crow + (M_ >> 2) * 64 + (M_ & 3) * 16;
#pragma unroll
    for (int N_ = 0; N_ < 4; N_++) {
      const int cg = ccol + (N_ >> 1) * 32 + (N_ & 1) * 16;
      if (cg < Nreal) {
#pragma unroll
        for (int j = 0; j < 4; j++)
          C[(size_t)(r + j) * Nreal + cg] = acc[M_][N_][j];
      }
    }
  }
}

// ---------------------------------------------------------------------------
// Host
// ---------------------------------------------------------------------------
extern "C" void kernel_launch(void* const* d_in, const int* in_sizes, int n_in,
                              void* d_out, int out_size, void* d_ws, size_t ws_size,
                              hipStream_t stream) {
  const int D = 1024, V = 50257, L = 8;
  const int M = 4096;
  const int Vpad = 50432;  // 197 * 256
  const size_t MD = (size_t)M * D;

  const int* ids = (const int*)d_in[0];
  const float* embedw = (const float*)d_in[1];
  const float* norm1_w = (const float*)d_in[2];
  const float* norm2_w = (const float*)d_in[3];
  const float* a_diag = (const float*)d_in[4];
  const float* W_in = (const float*)d_in[5];
  const float* b_in = (const float*)d_in[6];
  const float* W_out = (const float*)d_in[7];
  const float* ff_w1 = (const float*)d_in[8];
  const float* ff_b1 = (const float*)d_in[9];
  const float* ff_w2 = (const float*)d_in[10];
  const float* ff_b2 = (const float*)d_in[11];
  const float* final_norm_w = (const float*)d_in[12];
  const float* lm_head_w = (const float*)d_in[13];

  char* w = (char*)d_ws;
  float* x = (float*)w;   w += MD * 4;
  u16* h = (u16*)w;       w += MD * 2;
  float* pre = (float*)w; w += MD * 4;
  u16* hs = (u16*)w;      w += MD * 2;
  u16* hff = (u16*)w;     w += MD * 2 * 2;
  u16* WinT = (u16*)w;    w += (size_t)L * D * D * 2;
  u16* WoutT = (u16*)w;   w += (size_t)L * D * D * 2;
  u16* ffw1T = (u16*)w;   w += (size_t)L * 2 * D * D * 2;
  u16* ffw2T = (u16*)w;   w += (size_t)L * 2 * D * D * 2;
  u16* lmpad = (u16*)w;   w += (size_t)Vpad * D * 2;

  prep_weights<<<49152, dim3(32, 8), 0, stream>>>(
      W_in, W_out, ff_w1, ff_w2, WinT, WoutT, ffw1T, ffw2T);

  // cooperative mega kernel (lm_cast + embed + layers + final norm)
  void* args[] = {
      (void*)&ids,  (void*)&embedw, (void*)&norm1_w, (void*)&norm2_w,
      (void*)&a_diag, (void*)&b_in, (void*)&ff_b1,   (void*)&ff_b2,
      (void*)&final_norm_w, (void*)&lm_head_w,
      (void*)&x, (void*)&h, (void*)&pre, (void*)&hs, (void*)&hff,
      (void*)&WinT, (void*)&WoutT, (void*)&ffw1T, (void*)&ffw2T,
      (void*)&lmpad};
  hipError_t err = hipLaunchCooperativeKernel((const void*)mega, dim3(256),
                                              dim3(512), args, 0, stream);
  if (err != hipSuccess) {
    // fallback: round-8-validated multi-kernel sequence (identical output)
    lm_cast_kernel<<<Vpad, 256, 0, stream>>>(lm_head_w, lmpad);
    embed_kernel<<<M, 256, 0, stream>>>(ids, embedw, x);
    for (int l = 0; l < L; l++) {
      rmsnorm_kernel<<<M, 256, 0, stream>>>(x, norm1_w + (size_t)l * D, h);
      gemmL<0><<<dim3(8, 64), 256, 0, stream>>>(
          h, D, WinT + (size_t)l * D * D, D, nullptr, pre, nullptr, D, D);
      scan_kernel<<<8, 256, 0, stream>>>(pre, a_diag + (size_t)l * D,
                                         b_in + (size_t)l * D, hs);
      gemmL<1><<<dim3(8, 64), 256, 0, stream>>>(
          hs, D, WoutT + (size_t)l * D * D, D, nullptr, x, nullptr, D, D);
      rmsnorm_kernel<<<M, 256, 0, stream>>>(x, norm2_w + (size_t)l * D, h);
      gemmL<2><<<dim3(16, 64), 256, 0, stream>>>(
          h, D, ffw1T + (size_t)l * 2 * D * D, D, ff_b1 + (size_t)l * 2 * D,
          nullptr, hff, 2 * D, D);
      gemmL<3><<<dim3(8, 64), 256, 0, stream>>>(
          hff, 2 * D, ffw2T + (size_t)l * 2 * D * D, 2 * D,
          ff_b2 + (size_t)l * D, x, nullptr, D, 2 * D);
    }
    rmsnorm_kernel<<<M, 256, 0, stream>>>(x, final_norm_w, h);
  }

  gemm_lm8<<<dim3(8 * 394), 512, 0, stream>>>(h, lmpad, (float*)d_out, V);
}

// Round 12
// 2702.206 us; speedup vs baseline: 2.2098x; 2.2098x over previous
//
#include <hip/hip_runtime.h>

typedef unsigned short u16;
typedef __bf16 bf16x8 __attribute__((ext_vector_type(8)));
typedef float f32x4 __attribute__((ext_vector_type(4)));
typedef unsigned short u16x4 __attribute__((ext_vector_type(4)));

__device__ __forceinline__ u16 f2bf(float f) {
  union { float f; unsigned int u; } v; v.f = f;
  return (u16)((v.u + 0x7FFFu + ((v.u >> 16) & 1u)) >> 16);
}

__device__ __forceinline__ void gload16(const void* g, void* l) {
  __builtin_amdgcn_global_load_lds(
      (const __attribute__((address_space(1))) unsigned int*)g,
      (__attribute__((address_space(3))) unsigned int*)l, 16, 0, 0);
}

// ---------------------------------------------------------------------------
// prep_all: weight transposes + lm-head cast/pad + embedding gather in ONE
// dispatch (flat grid, branch by bid; all parts independent).
//   bid [0, 49152)          : W transposes (validated prep_weights logic)
//   bid [49152, 49152+50432): lm cast row
//   bid [99584, 99584+4096) : embed row
// ---------------------------------------------------------------------------
__global__ __launch_bounds__(256) void prep_all(
    const float* __restrict__ Win, const float* __restrict__ Wout,
    const float* __restrict__ ffw1, const float* __restrict__ ffw2,
    u16* __restrict__ WinT, u16* __restrict__ WoutT,
    u16* __restrict__ f1T, u16* __restrict__ f2T,
    const float* __restrict__ lmw, u16* __restrict__ lmpad,
    const int* __restrict__ ids, const float* __restrict__ embedw,
    float* __restrict__ x) {
  __shared__ float tile[32][33];
  const int bid = blockIdx.x;
  const int tid = threadIdx.x;

  if (bid >= 49152 + 50432) {  // embed
    const int row = bid - (49152 + 50432);
    *(float4*)(x + (size_t)row * 1024 + tid * 4) =
        *(const float4*)(embedw + (size_t)ids[row] * 1024 + tid * 4);
    return;
  }
  if (bid >= 49152) {  // lm cast (pad rows zero)
    const int row = bid - 49152;
    u16x4 o = {0, 0, 0, 0};
    if (row < 50257) {
      float4 v = *(const float4*)(lmw + (size_t)row * 1024 + tid * 4);
      o.x = f2bf(v.x); o.y = f2bf(v.y); o.z = f2bf(v.z); o.w = f2bf(v.w);
    }
    *(u16x4*)(lmpad + (size_t)row * 1024 + tid * 4) = o;
    return;
  }

  // weight transpose tile (32x32), W (R x C) -> WT (C x R) bf16
  const int tk = bid;
  const float* src; u16* dst;
  int R, C, tr, tc;
  if (tk < 8192) {
    const int l = tk >> 10, rem = tk & 1023;
    R = 1024; C = 1024; tr = rem >> 5; tc = rem & 31;
    src = Win + (size_t)l * 1048576; dst = WinT + (size_t)l * 1048576;
  } else if (tk < 16384) {
    const int q = tk - 8192, l = q >> 10, rem = q & 1023;
    R = 1024; C = 1024; tr = rem >> 5; tc = rem & 31;
    src = Wout + (size_t)l * 1048576; dst = WoutT + (size_t)l * 1048576;
  } else if (tk < 32768) {
    const int q = tk - 16384, l = q >> 11, rem = q & 2047;
    R = 1024; C = 2048; tr = rem >> 6; tc = rem & 63;
    src = ffw1 + (size_t)l * 2097152; dst = f1T + (size_t)l * 2097152;
  } else {
    const int q = tk - 32768, l = q >> 11, rem = q & 2047;
    R = 2048; C = 1024; tr = rem >> 5; tc = rem & 31;
    src = ffw2 + (size_t)l * 2097152; dst = f2T + (size_t)l * 2097152;
  }
  const int tx = tid & 31, ty = tid >> 5;
  const int c0 = tc * 32, r0 = tr * 32;
#pragma unroll
  for (int k = 0; k < 32; k += 8)
    tile[ty + k][tx] = src[(size_t)(r0 + ty + k) * C + (c0 + tx)];
  __syncthreads();
#pragma unroll
  for (int k = 0; k < 32; k += 8)
    dst[(size_t)(c0 + ty + k) * R + (r0 + tx)] = f2bf(tile[tx][ty + k]);
}

// ---------------------------------------------------------------------------
// RMSNorm: f32 in -> bf16 out (D = 1024, one block per row)
// ---------------------------------------------------------------------------
__global__ void rmsnorm_kernel(const float* __restrict__ x, const float* __restrict__ w,
                               u16* __restrict__ out) {
  const int row = blockIdx.x, tid = threadIdx.x;
  const float* xr = x + (size_t)row * 1024;
  float4 v = *(const float4*)(xr + tid * 4);
  float ss = v.x * v.x + v.y * v.y + v.z * v.z + v.w * v.w;
#pragma unroll
  for (int off = 32; off; off >>= 1) ss += __shfl_xor(ss, off);
  __shared__ float red[4];
  if ((tid & 63) == 0) red[tid >> 6] = ss;
  __syncthreads();
  const float tot = red[0] + red[1] + red[2] + red[3];
  const float r = rsqrtf(tot * (1.0f / 1024.0f) + 1e-6f);
  float4 wv = *(const float4*)(w + tid * 4);
  u16x4 o;
  o.x = f2bf(v.x * r * wv.x); o.y = f2bf(v.y * r * wv.y);
  o.z = f2bf(v.z * r * wv.z); o.w = f2bf(v.w * r * wv.w);
  *(u16x4*)(out + (size_t)row * 1024 + tid * 4) = o;
}

// ---------------------------------------------------------------------------
// Sequential chaotic scan (b_in folded)
// ---------------------------------------------------------------------------
__device__ __forceinline__ void sload(const float* __restrict__ p, int tb,
                                      float A2b, float (&buf)[8]) {
#pragma unroll
  for (int j = 0; j < 8; j++)
    buf[j] = fmaf(p[(size_t)(tb + j) * 1024], 2.8853900817779268f, A2b);
}

__device__ __forceinline__ void scomp(float (&buf)[8], float m2A2, float& r,
                                      u16* __restrict__ o, int tb) {
#pragma unroll
  for (int j = 0; j < 8; j++) {
    float z = fmaf(m2A2, r, buf[j]);
    float e = __builtin_amdgcn_exp2f(z);
    r = __builtin_amdgcn_rcpf(1.0f + e);
    o[(size_t)(tb + j) * 1024] = f2bf(fmaf(-2.0f, r, 1.0f));
  }
}

__global__ __launch_bounds__(256) void scan_kernel(const float* __restrict__ pre,
                                                   const float* __restrict__ a_diag,
                                                   const float* __restrict__ b_in,
                                                   u16* __restrict__ hs) {
  const int T = 2048;
  const int idx = blockIdx.x * 256 + threadIdx.x;  // 0..2047
  const int b = idx >> 10, d = idx & 1023;
  const float* p = pre + (size_t)b * T * 1024 + d;
  u16* o = hs + (size_t)b * T * 1024 + d;
  const float A2 = a_diag[d] * 2.8853900817779268f;
  const float A2b = fmaf(2.8853900817779268f, b_in[d], A2);
  const float m2A2 = -2.0f * A2;
  float r = 0.5f;
  float b0[8], b1[8], b2[8], b3[8];
  sload(p, 0, A2b, b0); sload(p, 8, A2b, b1);
  sload(p, 16, A2b, b2); sload(p, 24, A2b, b3);
  for (int t0 = 0; t0 < T; t0 += 32) {
    scomp(b0, m2A2, r, o, t0);
    if (t0 + 32 < T) sload(p, t0 + 32, A2b, b0);
    scomp(b1, m2A2, r, o, t0 + 8);
    if (t0 + 32 < T) sload(p, t0 + 40, A2b, b1);
    scomp(b2, m2A2, r, o, t0 + 16);
    if (t0 + 32 < T) sload(p, t0 + 48, A2b, b2);
    scomp(b3, m2A2, r, o, t0 + 24);
    if (t0 + 32 < T) sload(p, t0 + 56, A2b, b3);
  }
}

// ---------------------------------------------------------------------------
// gemmL: layer GEMM, NT bf16. 64x128 tile, BK=64, 4 waves, counted-vmcnt(6)
// 2-phase dbuf (round-8 validated best). Residual/bias/silu fused.
// EPI: 0 Cf=v; 1 Cf+=v; 2 Cb=silu(v+bias); 3 Cf+=v+bias
// ---------------------------------------------------------------------------
template <int EPI>
__global__ __launch_bounds__(256) void gemmL(
    const u16* __restrict__ A, int lda, const u16* __restrict__ Bw, int ldb,
    const float* __restrict__ bias, float* Cf, u16* __restrict__ Cb,
    int ldc, int K) {
  __shared__ char lds[49152];  // 2 x [A 8K | B 16K]
  const int tid = threadIdx.x;
  const int lane = tid & 63;
  const int wc = tid >> 6;
  const int tm = blockIdx.y * 64, tn = blockIdx.x * 128;
  const int lr = lane & 15;
  const int sb0 = ((lane >> 4) ^ (lane & 7)) << 4;

  const int srow = tid >> 3;  // 0..31
  const int sxs = ((tid & 7) ^ (srow & 7)) << 4;
  const char* pA = (const char*)A + (size_t)(tm + srow) * lda * 2 + sxs;
  const char* pB = (const char*)Bw + (size_t)(tn + srow) * ldb * 2 + sxs;
  const size_t a32 = (size_t)lda * 64;
  const size_t b32 = (size_t)ldb * 64;

#define STGL(kt, bufo)                                \
  {                                                   \
    char* d = lds + (bufo) + tid * 16;                \
    const size_t kb = (size_t)(kt) << 7;              \
    gload16(pA + kb, d);                              \
    gload16(pA + a32 + kb, d + 4096);                 \
    gload16(pB + kb, d + 8192);                       \
    gload16(pB + b32 + kb, d + 12288);                \
    gload16(pB + 2 * b32 + kb, d + 16384);            \
    gload16(pB + 3 * b32 + kb, d + 20480);            \
  }

  f32x4 acc[4][2] = {};
  const int nkt = K >> 6;

  STGL(0, 0);
  int cur = 0;
  for (int kt = 0; kt < nkt; ++kt) {
    if (kt + 1 < nkt) {
      STGL(kt + 1, (cur ^ 1) * 24576);
      asm volatile("s_waitcnt vmcnt(6)" ::: "memory");
    } else {
      asm volatile("s_waitcnt vmcnt(0)" ::: "memory");
    }
    __builtin_amdgcn_s_barrier();
    const char* base = lds + cur * 24576;
    bf16x8 aF[4][2], bF[2][2];
#pragma unroll
    for (int m = 0; m < 4; m++)
#pragma unroll
      for (int ks = 0; ks < 2; ks++)
        aF[m][ks] =
            *(const bf16x8*)(base + (m * 16 + lr) * 128 + (sb0 ^ (ks << 6)));
#pragma unroll
    for (int n = 0; n < 2; n++)
#pragma unroll
      for (int ks = 0; ks < 2; ks++)
        bF[n][ks] = *(const bf16x8*)(base + 8192 +
                                     (wc * 32 + n * 16 + lr) * 128 +
                                     (sb0 ^ (ks << 6)));
#pragma unroll
    for (int ks = 0; ks < 2; ks++)
#pragma unroll
      for (int m = 0; m < 4; m++)
#pragma unroll
        for (int n = 0; n < 2; n++)
          acc[m][n] = __builtin_amdgcn_mfma_f32_16x16x32_bf16(
              aF[m][ks], bF[n][ks], acc[m][n], 0, 0, 0);
    __builtin_amdgcn_s_barrier();
    cur ^= 1;
  }
#undef STGL

  const int crow = tm + ((lane >> 4) << 2);
  const int ccol = tn + wc * 32 + lr;
#pragma unroll
  for (int m = 0; m < 4; m++) {
#pragma unroll
    for (int n = 0; n < 2; n++) {
      const int cg = ccol + n * 16;
      float bb = 0.0f;
      if (EPI == 2 || EPI == 3) bb = bias[cg];
#pragma unroll
      for (int j = 0; j < 4; j++) {
        const size_t off = (size_t)(crow + m * 16 + j) * ldc + cg;
        const float v = acc[m][n][j] + bb;
        if (EPI == 0) {
          Cf[off] = v;
        } else if (EPI == 1) {
          Cf[off] += v;
        } else if (EPI == 2) {
          const float sg = __builtin_amdgcn_rcpf(
              1.0f + __builtin_amdgcn_exp2f(-1.4426950408889634f * v));
          Cb[off] = f2bf(v * sg);
        } else {
          Cf[off] += v;
        }
      }
    }
  }
}

// ---------------------------------------------------------------------------
// gemm_lm8: 256x256 / BK=64 / 8 waves / 8-phase counted-vmcnt, plain stores
// (round-9/10 validated: ~515us).
// ---------------------------------------------------------------------------
__global__ __launch_bounds__(512, 2) void gemm_lm8(
    const u16* __restrict__ A, const u16* __restrict__ Bw,
    float* __restrict__ C, int Nreal) {
  __shared__ char lds[131072];
  const int tid = threadIdx.x;
  const int lane = tid & 63;
  const int wid = tid >> 6;
  const int wr = wid >> 2;
  const int wc = wid & 3;
  const int bid = blockIdx.x;
  const int tm = (((bid & 7) << 1) + ((bid >> 3) & 1)) << 8;
  const int tn = (bid >> 4) << 8;

  const int srow = tid >> 3;
  const int sxor = ((tid & 7) ^ (srow & 7)) << 4;
  const char* pAs = (const char*)A + ((size_t)(tm + srow) << 11) + sxor;
  const char* pBs = (const char*)Bw + ((size_t)(tn + srow) << 11) + sxor;

#define STG(p, h, kt, ro)                                      \
  {                                                            \
    char* d = lds + (ro) + tid * 16;                           \
    const char* s = (p) + ((size_t)(h) << 18) + ((kt) << 7);   \
    gload16(s, d);                                             \
    gload16(s + (64ull << 11), d + 8192);                      \
  }

  const int lr = lane & 15;
  const int sb0 = (((lane >> 4) ^ (lane & 7)) << 4);
  const int sb[2] = {sb0, sb0 ^ 64};
  const int aB = wr * 16384 + lr * 128;
  const int bB = 32768 + (wc >> 1) * 16384 + ((wc & 1) * 64 + lr) * 128;

  bf16x8 aR[4][2], bR[2][2][2];
  f32x4 acc[8][4] = {};

#define LDA_Q(bufo, mq)                                                         \
  _Pragma("unroll") for (int m_ = 0; m_ < 4; m_++)                              \
  _Pragma("unroll") for (int k_ = 0; k_ < 2; k_++)                              \
      aR[m_][k_] = *(const bf16x8*)(lds + (bufo) + aB + (mq)*8192 + m_*2048 + sb[k_]);

#define LDB_Q(bufo, nq)                                                         \
  _Pragma("unroll") for (int n_ = 0; n_ < 2; n_++)                              \
  _Pragma("unroll") for (int k_ = 0; k_ < 2; k_++)                              \
      bR[nq][n_][k_] = *(const bf16x8*)(lds + (bufo) + bB + (nq)*4096 + n_*2048 + sb[k_]);

#define MFMA_Q(mq, nq)                                                          \
  __builtin_amdgcn_s_setprio(1);                                                \
  _Pragma("unroll") for (int m_ = 0; m_ < 4; m_++)                              \
  _Pragma("unroll") for (int n_ = 0; n_ < 2; n_++)                              \
  _Pragma("unroll") for (int k_ = 0; k_ < 2; k_++)                              \
      acc[(mq)*4 + m_][(nq)*2 + n_] = __builtin_amdgcn_mfma_f32_16x16x32_bf16(  \
          aR[m_][k_], bR[nq][n_][k_], acc[(mq)*4 + m_][(nq)*2 + n_], 0, 0, 0);  \
  __builtin_amdgcn_s_setprio(0);

#define BAR() __builtin_amdgcn_s_barrier()
#define LGKM0() asm volatile("s_waitcnt lgkmcnt(0)" ::: "memory")

  STG(pAs, 0, 0, 0);
  STG(pAs, 1, 0, 16384);
  STG(pBs, 0, 0, 32768);
  STG(pBs, 1, 0, 49152);
  STG(pBs, 0, 1, 65536 + 32768);
  STG(pBs, 1, 1, 65536 + 49152);
  asm volatile("s_waitcnt vmcnt(4)" ::: "memory");
  BAR();

  for (int it = 0; it < 8; ++it) {
    const int t1 = 2 * it + 1, t2 = 2 * it + 2, t3 = 2 * it + 3;
    const bool st = (it < 7);
    LDA_Q(0, 0); LDB_Q(0, 0);
    STG(pAs, 0, t1, 65536);
    BAR(); LGKM0(); MFMA_Q(0, 0); BAR();
    LDB_Q(0, 1);
    STG(pAs, 1, t1, 65536 + 16384);
    BAR(); LGKM0(); MFMA_Q(0, 1); BAR();
    LDA_Q(0, 1);
    if (st) STG(pBs, 0, t2, 32768);
    BAR(); LGKM0(); MFMA_Q(1, 0); BAR();
    if (st) STG(pBs, 1, t2, 49152);
    BAR(); LGKM0(); MFMA_Q(1, 1);
    if (st) { asm volatile("s_waitcnt vmcnt(4)" ::: "memory"); }
    else    { asm volatile("s_waitcnt vmcnt(0)" ::: "memory"); }
    BAR();
    LDA_Q(65536, 0); LDB_Q(65536, 0);
    if (st) STG(pAs, 0, t2, 0);
    BAR(); LGKM0(); MFMA_Q(0, 0); BAR();
    LDB_Q(65536, 1);
    if (st) STG(pAs, 1, t2, 16384);
    BAR(); LGKM0(); MFMA_Q(0, 1); BAR();
    LDA_Q(65536, 1);
    if (st) STG(pBs, 0, t3, 65536 + 32768);
    BAR(); LGKM0(); MFMA_Q(1, 0); BAR();
    if (st) STG(pBs, 1, t3, 65536 + 49152);
    BAR(); LGKM0(); MFMA_Q(1, 1);
    if (st) { asm volatile("s_waitcnt vmcnt(4)" ::: "memory"); }
    else    { asm volatile("s_waitcnt vmcnt(0)" ::: "memory"); }
    BAR();
  }
#undef STG
#undef LDA_Q
#undef LDB_Q
#undef MFMA_Q
#undef BAR
#undef LGKM0

  const int crow = tm + wr * 128 + ((lane >> 4) << 2);
  const int ccol = tn + wc * 64 + lr;
#pragma unroll
  for (int M_ = 0; M_ < 8; M_++) {
    const int r = crow + (M_ >> 2) * 64 + (M_ & 3) * 16;
#pragma unroll
    for (int N_ = 0; N_ < 4; N_++) {
      const int cg = ccol + (N_ >> 1) * 32 + (N_ & 1) * 16;
      if (cg < Nreal) {
#pragma unroll
        for (int j = 0; j < 4; j++)
          C[(size_t)(r + j) * Nreal + cg] = acc[M_][N_][j];
      }
    }
  }
}

// ---------------------------------------------------------------------------
// Host
// ---------------------------------------------------------------------------
extern "C" void kernel_launch(void* const* d_in, const int* in_sizes, int n_in,
                              void* d_out, int out_size, void* d_ws, size_t ws_size,
                              hipStream_t stream) {
  const int D = 1024, V = 50257, L = 8;
  const int M = 4096;
  const int Vpad = 50432;  // 197 * 256
  const size_t MD = (size_t)M * D;

  const int* ids = (const int*)d_in[0];
  const float* embedw = (const float*)d_in[1];
  const float* norm1_w = (const float*)d_in[2];
  const float* norm2_w = (const float*)d_in[3];
  const float* a_diag = (const float*)d_in[4];
  const float* W_in = (const float*)d_in[5];
  const float* b_in = (const float*)d_in[6];
  const float* W_out = (const float*)d_in[7];
  const float* ff_w1 = (const float*)d_in[8];
  const float* ff_b1 = (const float*)d_in[9];
  const float* ff_w2 = (const float*)d_in[10];
  const float* ff_b2 = (const float*)d_in[11];
  const float* final_norm_w = (const float*)d_in[12];
  const float* lm_head_w = (const float*)d_in[13];

  char* w = (char*)d_ws;
  float* x = (float*)w;   w += MD * 4;
  u16* h = (u16*)w;       w += MD * 2;
  float* pre = (float*)w; w += MD * 4;
  u16* hs = (u16*)w;      w += MD * 2;
  u16* hff = (u16*)w;     w += MD * 2 * 2;
  u16* WinT = (u16*)w;    w += (size_t)L * D * D * 2;
  u16* WoutT = (u16*)w;   w += (size_t)L * D * D * 2;
  u16* ffw1T = (u16*)w;   w += (size_t)L * 2 * D * D * 2;
  u16* ffw2T = (u16*)w;   w += (size_t)L * 2 * D * D * 2;
  u16* lmpad = (u16*)w;   w += (size_t)Vpad * D * 2;

  // all prep in one dispatch: transposes + lm cast + embed
  prep_all<<<49152 + Vpad + M, 256, 0, stream>>>(
      W_in, W_out, ff_w1, ff_w2, WinT, WoutT, ffw1T, ffw2T,
      lm_head_w, lmpad, ids, embedw, x);

  for (int l = 0; l < L; l++) {
    rmsnorm_kernel<<<M, 256, 0, stream>>>(x, norm1_w + (size_t)l * D, h);
    gemmL<0><<<dim3(8, 64), 256, 0, stream>>>(
        h, D, WinT + (size_t)l * D * D, D, nullptr, pre, nullptr, D, D);
    scan_kernel<<<8, 256, 0, stream>>>(pre, a_diag + (size_t)l * D,
                                       b_in + (size_t)l * D, hs);
    gemmL<1><<<dim3(8, 64), 256, 0, stream>>>(
        hs, D, WoutT + (size_t)l * D * D, D, nullptr, x, nullptr, D, D);
    rmsnorm_kernel<<<M, 256, 0, stream>>>(x, norm2_w + (size_t)l * D, h);
    gemmL<2><<<dim3(16, 64), 256, 0, stream>>>(
        h, D, ffw1T + (size_t)l * 2 * D * D, D, ff_b1 + (size_t)l * 2 * D,
        nullptr, hff, 2 * D, D);
    gemmL<3><<<dim3(8, 64), 256, 0, stream>>>(
        hff, 2 * D, ffw2T + (size_t)l * 2 * D * D, 2 * D,
        ff_b2 + (size_t)l * D, x, nullptr, D, 2 * D);
  }

  rmsnorm_kernel<<<M, 256, 0, stream>>>(x, final_norm_w, h);
  gemm_lm8<<<dim3(8 * 394), 512, 0, stream>>>(h, lmpad, (float*)d_out, V);
}